// Round 5
// baseline (516.599 us; speedup 1.0000x reference)
//
#include <hip/hip_runtime.h>

#define H_DIM 1024
#define I_DIM 512
#define NE 8
#define SI_DIM 1024
#define NT 2048
#define GRID 1024

typedef __bf16 bf16;
typedef __bf16 bf16x4 __attribute__((ext_vector_type(4)));
typedef __bf16 bf16x8 __attribute__((ext_vector_type(8)));
typedef float f32x4 __attribute__((ext_vector_type(4)));

// ---- bf16 weight buffer layout (elements), R4-verified interleave ----
#define W_GU 0ull
#define W_DN 8388608ull
#define W_SGU 12582912ull
#define W_SDN 14680064ull
#define W_TOT 15728640ull

#define NWB 15360  // weight-convert units
#define NRB 512    // router units
#define NZB 2048   // out-zero units
#define NU (NWB + NRB + NZB)

// ---- workspace (bytes, 16B aligned) ----
#define OFF_CNT 0
#define OFF_WM 64
#define OFF_TOPI 1024
#define OFF_TOPW (OFF_TOPI + NT * 8)
#define OFF_LISTS (OFF_TOPW + NT * 8)
#define OFF_WB (OFF_LISTS + NE * NT * 4)                  // bf16[W_TOT]
#define OFF_XB (OFF_WB + (size_t)W_TOT * 2)               // bf16[NT][H]
#define OFF_ACTE (OFF_XB + (size_t)NT * H_DIM * 2)        // bf16[NE][NT][I]
#define OFF_ACTS (OFF_ACTE + (size_t)NE * NT * I_DIM * 2) // bf16[NT][SI]
#define OFF_BAR (OFF_ACTS + (size_t)NT * SI_DIM * 2)      // unsigned[64]

__device__ __forceinline__ bf16x4 cvt4(f32x4 v) {
  bf16x4 r;
  r.x = (bf16)v.x; r.y = (bf16)v.y; r.z = (bf16)v.z; r.w = (bf16)v.w;
  return r;
}

__device__ __forceinline__ void glds16(const bf16* g, bf16* l) {
  __builtin_amdgcn_global_load_lds(
      (const __attribute__((address_space(1))) unsigned int*)g,
      (__attribute__((address_space(3))) unsigned int*)l, 16, 0, 0);
}

// device-scope grid barrier: one counter per sync point (memset to 0 before
// launch). __threadfence() = agent fence -> L2 writeback/inv across XCDs.
__device__ __forceinline__ void gsync(unsigned* bar) {
  __syncthreads();
  if (threadIdx.x == 0) {
    __threadfence();
    __hip_atomic_fetch_add(bar, 1u, __ATOMIC_RELAXED, __HIP_MEMORY_SCOPE_AGENT);
    while (__hip_atomic_load(bar, __ATOMIC_RELAXED, __HIP_MEMORY_SCOPE_AGENT) <
           (unsigned)GRID) {
      __builtin_amdgcn_s_sleep(4);
    }
    __threadfence();
  }
  __syncthreads();
}

// ---- single persistent kernel: P0 prep | P1 build | P2 gu | P3 down ----
__global__ __launch_bounds__(256, 4) void moe_kernel(
    const float* __restrict__ x, const float* __restrict__ gw,
    const float* __restrict__ lb, const float* __restrict__ eg,
    const float* __restrict__ eu, const float* __restrict__ ed,
    const float* __restrict__ sg, const float* __restrict__ su,
    const float* __restrict__ sd, bf16* __restrict__ wb,
    bf16* __restrict__ xb, int2* __restrict__ topi,
    float2* __restrict__ topw, int* __restrict__ cnt,
    float* __restrict__ wm, int* __restrict__ lists,
    bf16* __restrict__ act_e, bf16* __restrict__ act_s,
    float* __restrict__ out, unsigned* __restrict__ bar) {
  const int tid = threadIdx.x;
  const int bid = blockIdx.x;
  __shared__ __align__(16) char smem[24832];
  bf16* As = (bf16*)smem;                  // 8KB  (64x64)
  bf16* Bs = (bf16*)(smem + 8192);         // 16KB (128x64)
  int* rows_s = (int*)(smem + 24576);      // 256B

  // ============ P0: weight convert + router(+x convert) + out zero ============
  for (int u = bid; u < NU; u += GRID) {
    if (u < NWB) {
      size_t i = ((size_t)u * 256 + tid) * 4;
      const float* src;
      if (i < W_DN) {
        size_t z = i >> 20;
        int rem = (int)(i & ((1u << 20) - 1));
        int rp = rem >> 10, k = rem & 1023;
        int b = rp >> 4;
        int sr = ((b >> 1) << 4) | (rp & 15);
        src = ((b & 1) ? eu : eg) + (z << 19) + ((size_t)sr << 10) + k;
      } else if (i < W_SGU) {
        src = ed + (i - W_DN);
      } else if (i < W_SDN) {
        int rem = (int)(i - W_SGU);
        int rp = rem >> 10, k = rem & 1023;
        int b = rp >> 4;
        int sr = ((b >> 1) << 4) | (rp & 15);
        src = ((b & 1) ? su : sg) + ((size_t)sr << 10) + k;
      } else {
        src = sd + (i - W_SDN);
      }
      *(bf16x4*)(wb + i) = cvt4(*(const f32x4*)src);
    } else if (u < NWB + NRB) {
      const int lane = tid & 63;
      const int t = (u - NWB) * 4 + (tid >> 6);
      const float* xr = x + (size_t)t * H_DIM;
      bf16* xw = xb + (size_t)t * H_DIM;
      float s[NE];
#pragma unroll
      for (int e = 0; e < NE; e++) s[e] = 0.f;
#pragma unroll
      for (int k0 = 0; k0 < H_DIM; k0 += 256) {
        f32x4 xv = *(const f32x4*)(xr + k0 + lane * 4);
        *(bf16x4*)(xw + k0 + lane * 4) = cvt4(xv);
#pragma unroll
        for (int e = 0; e < NE; e++) {
          f32x4 gv = *(const f32x4*)(gw + e * H_DIM + k0 + lane * 4);
          s[e] += xv.x * gv.x + xv.y * gv.y + xv.z * gv.z + xv.w * gv.w;
        }
      }
#pragma unroll
      for (int e = 0; e < NE; e++) {
        float v = s[e];
#pragma unroll
        for (int off = 32; off > 0; off >>= 1) v += __shfl_xor(v, off);
        s[e] = v;
      }
      if (lane == 0) {
        float sc[NE];
#pragma unroll
        for (int e = 0; e < NE; e++) sc[e] = 1.f / (1.f + expf(-(s[e] + lb[e])));
        int i1 = 0;
#pragma unroll
        for (int e = 1; e < NE; e++)
          if (sc[e] > sc[i1]) i1 = e;  // ties -> lowest index (lax.top_k)
        int i2 = -1;
#pragma unroll
        for (int e = 0; e < NE; e++) {
          if (e == i1) continue;
          if (i2 < 0 || sc[e] > sc[i2]) i2 = e;
        }
        float w1 = sc[i1], w2 = sc[i2];
        float inv = 1.f / (w1 + w2 + 1e-8f);
        topi[t] = make_int2(i1, i2);
        topw[t] = make_float2(w1 * inv, w2 * inv);
      }
    } else {
      size_t j = ((size_t)(u - NWB - NRB) * 256 + tid) * 4;
      f32x4 zz = {0.f, 0.f, 0.f, 0.f};
      *(f32x4*)(out + j) = zz;
    }
  }
  gsync(bar + 0);

  // ============ P1: build lists (blocks 0..7, one per expert) ============
  if (bid < NE) {
    const int e = bid;
    const int wave = tid >> 6, lane = tid & 63;
    int* wc = rows_s;
    float* wf = (float*)(rows_s + 8);
    const int tbeg = wave * (NT / 4), tend = tbeg + NT / 4;
    int c = 0;
    float wa = 0.f;
    for (int t0 = tbeg; t0 < tend; t0 += 64) {
      int2 ti = topi[t0 + lane];
      float2 tw = topw[t0 + lane];
      bool hit = (ti.x == e) || (ti.y == e);
      float w = (ti.x == e) ? tw.x : ((ti.y == e) ? tw.y : 0.f);
      c += __popcll(__ballot(hit));
#pragma unroll
      for (int off = 32; off > 0; off >>= 1) w += __shfl_xor(w, off);
      wa += w;
    }
    if (lane == 0) { wc[wave] = c; wf[wave] = wa; }
    __syncthreads();
    int pos = 0;
    for (int w = 0; w < wave; w++) pos += wc[w];
    for (int t0 = tbeg; t0 < tend; t0 += 64) {
      int t = t0 + lane;
      int2 ti = topi[t];
      bool hit = (ti.x == e) || (ti.y == e);
      unsigned long long m = __ballot(hit);
      int pre = __popcll(m & ((1ull << lane) - 1ull));
      if (hit) lists[e * NT + pos + pre] = t;
      pos += __popcll(m);
    }
    if (tid == 0) {
      int ctot = wc[0] + wc[1] + wc[2] + wc[3];
      cnt[e] = ctot;
      wm[e] = (wf[0] + wf[1] + wf[2] + wf[3]) / (float)(ctot > 0 ? ctot : 1);
    }
  }
  gsync(bar + 16);

  const int lane = tid & 63, wave = tid >> 6;
  const int mw = (wave & 1) * 32, nw = (wave >> 1) * 64;
  const int l15 = lane & 15, quad = lane >> 4;
  const int srow = tid >> 3;   // 0..31
  const int cch = tid & 7;     // 16B chunk id
  const int p8 = cch * 8;
  const int sx = (l15 & 7) * 8;

  // ============ P2: gate+up GEMM, 64x128 tiles (R1-proven inner loop) ====
  // vb<512: shared (ct=s&15, rt=s>>4) on bids 0..511.
  // vb>=512: routed r0=vb-512: z=r0&7, ct=(r0>>3)&7, rt=r0>>6 — real tiles
  // (rt<~8) land on bids 512..1023 first pass; expert z -> XCD z.
  for (int vb = bid; vb < 2560; vb += GRID) {
    int z, ct, rt;
    if (vb < 512) { z = NE; ct = vb & 15; rt = vb >> 4; }
    else { int r0 = vb - 512; z = r0 & 7; ct = (r0 >> 3) & 7; rt = r0 >> 6; }
    int mrem, ldc;
    bf16* Cb;
    const bf16* Bb;
    if (z < NE) {
      int c = cnt[z];
      if (rt * 64 >= c) continue;
      mrem = c - rt * 64;
      Bb = wb + W_GU + ((size_t)z << 20) + (size_t)ct * 128 * H_DIM;
      Cb = act_e + ((size_t)z * NT + rt * 64) * I_DIM;
      ldc = I_DIM;
    } else {
      mrem = 64;
      Bb = wb + W_SGU + (size_t)ct * 128 * H_DIM;
      Cb = act_s + (size_t)rt * 64 * SI_DIM;
      ldc = SI_DIM;
    }
    if (tid < 64)
      rows_s[tid] = (z < NE)
          ? lists[z * NT + rt * 64 + (tid < mrem ? tid : mrem - 1)]
          : rt * 64 + tid;
    __syncthreads();
    const bf16 *ap[2], *bp[4];
    int alo[2], blo[4];
#pragma unroll
    for (int r = 0; r < 2; r++) {
      int R = srow + r * 32;
      int gs = (cch ^ (R & 7)) * 8;
      ap[r] = xb + (size_t)rows_s[R] * H_DIM + gs;
      alo[r] = R * 64 + p8;
    }
#pragma unroll
    for (int r = 0; r < 4; r++) {
      int R = srow + r * 32;
      int gs = (cch ^ (R & 7)) * 8;
      bp[r] = Bb + (size_t)R * H_DIM + gs;
      blo[r] = R * 64 + p8;
    }
    f32x4 acc[2][4] = {};
    for (int k0 = 0; k0 < H_DIM; k0 += 64) {
#pragma unroll
      for (int r = 0; r < 2; r++) glds16(ap[r] + k0, &As[alo[r]]);
#pragma unroll
      for (int r = 0; r < 4; r++) glds16(bp[r] + k0, &Bs[blo[r]]);
      __syncthreads();
#pragma unroll
      for (int kk = 0; kk < 2; kk++) {
        const int ko = (kk * 4 + quad) * 8;
        bf16x8 av[2], bv[4];
#pragma unroll
        for (int i = 0; i < 2; i++)
          av[i] = *(const bf16x8*)&As[(mw + i * 16 + l15) * 64 + (ko ^ sx)];
#pragma unroll
        for (int j = 0; j < 4; j++)
          bv[j] = *(const bf16x8*)&Bs[(nw + j * 16 + l15) * 64 + (ko ^ sx)];
#pragma unroll
        for (int i = 0; i < 2; i++)
#pragma unroll
          for (int j = 0; j < 4; j++)
            acc[i][j] = __builtin_amdgcn_mfma_f32_16x16x32_bf16(
                av[i], bv[j], acc[i][j], 0, 0, 0);
      }
      __syncthreads();
    }
    // j even = gate, j odd = up
#pragma unroll
    for (int i = 0; i < 2; i++) {
#pragma unroll
      for (int rg = 0; rg < 4; rg++) {
        int rl = mw + i * 16 + quad * 4 + rg;
        if (rl < mrem) {
#pragma unroll
          for (int jp = 0; jp < 2; jp++) {
            float g = acc[i][jp * 2][rg];
            float u = acc[i][jp * 2 + 1][rg];
            int c = ct * 64 + (nw >> 1) + jp * 16 + l15;
            Cb[(size_t)rl * ldc + c] = (bf16)((g / (1.f + __expf(-g))) * u);
          }
        }
      }
    }
    __syncthreads();
  }
  gsync(bar + 32);

  // ============ P3: down GEMM, 64x128 tiles; atomicAdd epilogue ============
  // vb<256: shared (ct=vb&7, rt=vb>>3). vb>=256: routed r0=vb-256.
  for (int vb = bid; vb < 2304; vb += GRID) {
    int z, ct, rt;
    if (vb < 256) { z = NE; ct = vb & 7; rt = vb >> 3; }
    else { int r0 = vb - 256; z = r0 & 7; ct = (r0 >> 3) & 7; rt = r0 >> 6; }
    int K, mrem;
    const bf16 *Ab, *Bb;
    if (z < NE) {
      int c = cnt[z];
      if (rt * 64 >= c) continue;
      mrem = c - rt * 64;
      Ab = act_e + ((size_t)z * NT + rt * 64) * I_DIM;
      K = I_DIM;
      Bb = wb + W_DN + ((size_t)z << 19) + (size_t)ct * 128 * I_DIM;
    } else {
      mrem = 64;
      Ab = act_s + (size_t)rt * 64 * SI_DIM;
      K = SI_DIM;
      Bb = wb + W_SDN + (size_t)ct * 128 * SI_DIM;
    }
    if (tid < 64)
      rows_s[tid] = (z < NE)
          ? lists[z * NT + rt * 64 + (tid < mrem ? tid : mrem - 1)]
          : rt * 64 + tid;
    __syncthreads();
    const bf16 *ap[2], *bp[4];
    int alo[2], blo[4];
#pragma unroll
    for (int r = 0; r < 2; r++) {
      int R = srow + r * 32;
      int gs = (cch ^ (R & 7)) * 8;
      ap[r] = Ab + (size_t)R * K + gs;
      alo[r] = R * 64 + p8;
    }
#pragma unroll
    for (int r = 0; r < 4; r++) {
      int R = srow + r * 32;
      int gs = (cch ^ (R & 7)) * 8;
      bp[r] = Bb + (size_t)R * K + gs;
      blo[r] = R * 64 + p8;
    }
    f32x4 acc[2][4] = {};
    for (int k0 = 0; k0 < K; k0 += 64) {
#pragma unroll
      for (int r = 0; r < 2; r++) glds16(ap[r] + k0, &As[alo[r]]);
#pragma unroll
      for (int r = 0; r < 4; r++) glds16(bp[r] + k0, &Bs[blo[r]]);
      __syncthreads();
#pragma unroll
      for (int kk = 0; kk < 2; kk++) {
        const int ko = (kk * 4 + quad) * 8;
        bf16x8 av[2], bv[4];
#pragma unroll
        for (int i = 0; i < 2; i++)
          av[i] = *(const bf16x8*)&As[(mw + i * 16 + l15) * 64 + (ko ^ sx)];
#pragma unroll
        for (int j = 0; j < 4; j++)
          bv[j] = *(const bf16x8*)&Bs[(nw + j * 16 + l15) * 64 + (ko ^ sx)];
#pragma unroll
        for (int i = 0; i < 2; i++)
#pragma unroll
          for (int j = 0; j < 4; j++)
            acc[i][j] = __builtin_amdgcn_mfma_f32_16x16x32_bf16(
                av[i], bv[j], acc[i][j], 0, 0, 0);
      }
      __syncthreads();
    }
    const float wsc = (z < NE) ? wm[z] : 1.f;
#pragma unroll
    for (int i = 0; i < 2; i++) {
#pragma unroll
      for (int rg = 0; rg < 4; rg++) {
        int rl = mw + i * 16 + quad * 4 + rg;
        if (rl < mrem) {
          int t = rows_s[rl];
          float* orow = out + (size_t)t * H_DIM + ct * 128 + nw;
#pragma unroll
          for (int j = 0; j < 4; j++)
            atomicAdd(&orow[j * 16 + l15], wsc * acc[i][j][rg]);
        }
      }
    }
    __syncthreads();
  }
}

extern "C" void kernel_launch(void* const* d_in, const int* in_sizes, int n_in,
                              void* d_out, int out_size, void* d_ws,
                              size_t ws_size, hipStream_t stream) {
  (void)in_sizes; (void)n_in; (void)out_size; (void)ws_size;
  const float* x  = (const float*)d_in[0];
  const float* gw = (const float*)d_in[1];
  const float* lb = (const float*)d_in[2];
  const float* eg = (const float*)d_in[3];
  const float* eu = (const float*)d_in[4];
  const float* ed = (const float*)d_in[5];
  const float* sg = (const float*)d_in[6];
  const float* su = (const float*)d_in[7];
  const float* sd = (const float*)d_in[8];
  float* out = (float*)d_out;
  char* ws = (char*)d_ws;

  int* cnt     = (int*)(ws + OFF_CNT);
  float* wm    = (float*)(ws + OFF_WM);
  int2* topi   = (int2*)(ws + OFF_TOPI);
  float2* topw = (float2*)(ws + OFF_TOPW);
  int* lists   = (int*)(ws + OFF_LISTS);
  bf16* wb     = (bf16*)(ws + OFF_WB);
  bf16* xb     = (bf16*)(ws + OFF_XB);
  bf16* act_e  = (bf16*)(ws + OFF_ACTE);
  bf16* act_s  = (bf16*)(ws + OFF_ACTS);
  unsigned* bar = (unsigned*)(ws + OFF_BAR);

  hipMemsetAsync(bar, 0, 256, stream);
  moe_kernel<<<GRID, 256, 0, stream>>>(x, gw, lb, eg, eu, ed, sg, su, sd, wb,
                                       xb, topi, topw, cnt, wm, lists, act_e,
                                       act_s, out, bar);
}

// Round 6
// 443.642 us; speedup vs baseline: 1.1645x; 1.1645x over previous
//
#include <hip/hip_runtime.h>

#define H_DIM 1024
#define I_DIM 512
#define NE 8
#define SI_DIM 1024
#define NT 2048
#define GRID 768

typedef __bf16 bf16;
typedef __bf16 bf16x4 __attribute__((ext_vector_type(4)));
typedef __bf16 bf16x8 __attribute__((ext_vector_type(8)));
typedef float f32x4 __attribute__((ext_vector_type(4)));

// ---- bf16 weight buffer layout (elements), R4-verified interleave ----
#define W_GU 0ull
#define W_DN 8388608ull
#define W_SGU 12582912ull
#define W_SDN 14680064ull
#define W_TOT 15728640ull

#define NWB 15360  // weight-convert units
#define NRB 512    // router units
#define NZB 2048   // out-zero units
#define NU (NWB + NRB + NZB)

// ---- workspace (bytes, 16B aligned) ----
#define OFF_CNT 0
#define OFF_WM 64
#define OFF_TOPI 1024
#define OFF_TOPW (OFF_TOPI + NT * 8)
#define OFF_LISTS (OFF_TOPW + NT * 8)
#define OFF_WB (OFF_LISTS + NE * NT * 4)                  // bf16[W_TOT]
#define OFF_XB (OFF_WB + (size_t)W_TOT * 2)               // bf16[NT][H]
#define OFF_ACTE (OFF_XB + (size_t)NT * H_DIM * 2)        // bf16[NE][NT][I]
#define OFF_ACTS (OFF_ACTE + (size_t)NE * NT * I_DIM * 2) // bf16[NT][SI]
#define OFF_BAR (OFF_ACTS + (size_t)NT * SI_DIM * 2)      // unsigned[64]

__device__ __forceinline__ bf16x4 cvt4(f32x4 v) {
  bf16x4 r;
  r.x = (bf16)v.x; r.y = (bf16)v.y; r.z = (bf16)v.z; r.w = (bf16)v.w;
  return r;
}

__device__ __forceinline__ void glds16(const bf16* g, bf16* l) {
  __builtin_amdgcn_global_load_lds(
      (const __attribute__((address_space(1))) unsigned int*)g,
      (__attribute__((address_space(3))) unsigned int*)l, 16, 0, 0);
}

// device-scope grid barrier: one counter per sync point (memset to 0 before
// launch). __threadfence() = agent fence -> L2 writeback/inv across XCDs.
__device__ __forceinline__ void gsync(unsigned* bar) {
  __syncthreads();
  if (threadIdx.x == 0) {
    __threadfence();
    __hip_atomic_fetch_add(bar, 1u, __ATOMIC_RELAXED, __HIP_MEMORY_SCOPE_AGENT);
    while (__hip_atomic_load(bar, __ATOMIC_RELAXED, __HIP_MEMORY_SCOPE_AGENT) <
           (unsigned)GRID) {
      __builtin_amdgcn_s_sleep(4);
    }
    __threadfence();
  }
  __syncthreads();
}

// ---- single persistent kernel: P0 prep | P1 build | P2 gu | P3 down ----
// __launch_bounds__(256,3): VGPR cap 170 (kernel needs ~92 -> NO spill;
// R5's (256,4) cap=64 spilled acc to scratch = 3x regression).
// GRID = 768 = 3 blocks/CU x 256 CU, co-resident by construction.
__global__ __launch_bounds__(256, 3) void moe_kernel(
    const float* __restrict__ x, const float* __restrict__ gw,
    const float* __restrict__ lb, const float* __restrict__ eg,
    const float* __restrict__ eu, const float* __restrict__ ed,
    const float* __restrict__ sg, const float* __restrict__ su,
    const float* __restrict__ sd, bf16* __restrict__ wb,
    bf16* __restrict__ xb, int2* __restrict__ topi,
    float2* __restrict__ topw, int* __restrict__ cnt,
    float* __restrict__ wm, int* __restrict__ lists,
    bf16* __restrict__ act_e, bf16* __restrict__ act_s,
    float* __restrict__ out, unsigned* __restrict__ bar) {
  const int tid = threadIdx.x;
  const int bid = blockIdx.x;
  __shared__ __align__(16) char smem[24832];
  bf16* As = (bf16*)smem;                  // 8KB  (64x64)
  bf16* Bs = (bf16*)(smem + 8192);         // 16KB (128x64)
  int* rows_s = (int*)(smem + 24576);      // 256B

  // ============ P0: weight convert + router(+x convert) + out zero ============
  for (int u = bid; u < NU; u += GRID) {
    if (u < NWB) {
      size_t i = ((size_t)u * 256 + tid) * 4;
      const float* src;
      if (i < W_DN) {
        size_t z = i >> 20;
        int rem = (int)(i & ((1u << 20) - 1));
        int rp = rem >> 10, k = rem & 1023;
        int b = rp >> 4;
        int sr = ((b >> 1) << 4) | (rp & 15);
        src = ((b & 1) ? eu : eg) + (z << 19) + ((size_t)sr << 10) + k;
      } else if (i < W_SGU) {
        src = ed + (i - W_DN);
      } else if (i < W_SDN) {
        int rem = (int)(i - W_SGU);
        int rp = rem >> 10, k = rem & 1023;
        int b = rp >> 4;
        int sr = ((b >> 1) << 4) | (rp & 15);
        src = ((b & 1) ? su : sg) + ((size_t)sr << 10) + k;
      } else {
        src = sd + (i - W_SDN);
      }
      *(bf16x4*)(wb + i) = cvt4(*(const f32x4*)src);
    } else if (u < NWB + NRB) {
      const int lane = tid & 63;
      const int t = (u - NWB) * 4 + (tid >> 6);
      const float* xr = x + (size_t)t * H_DIM;
      bf16* xw = xb + (size_t)t * H_DIM;
      float s[NE];
#pragma unroll
      for (int e = 0; e < NE; e++) s[e] = 0.f;
#pragma unroll
      for (int k0 = 0; k0 < H_DIM; k0 += 256) {
        f32x4 xv = *(const f32x4*)(xr + k0 + lane * 4);
        *(bf16x4*)(xw + k0 + lane * 4) = cvt4(xv);
#pragma unroll
        for (int e = 0; e < NE; e++) {
          f32x4 gv = *(const f32x4*)(gw + e * H_DIM + k0 + lane * 4);
          s[e] += xv.x * gv.x + xv.y * gv.y + xv.z * gv.z + xv.w * gv.w;
        }
      }
#pragma unroll
      for (int e = 0; e < NE; e++) {
        float v = s[e];
#pragma unroll
        for (int off = 32; off > 0; off >>= 1) v += __shfl_xor(v, off);
        s[e] = v;
      }
      if (lane == 0) {
        float sc[NE];
#pragma unroll
        for (int e = 0; e < NE; e++) sc[e] = 1.f / (1.f + expf(-(s[e] + lb[e])));
        int i1 = 0;
#pragma unroll
        for (int e = 1; e < NE; e++)
          if (sc[e] > sc[i1]) i1 = e;  // ties -> lowest index (lax.top_k)
        int i2 = -1;
#pragma unroll
        for (int e = 0; e < NE; e++) {
          if (e == i1) continue;
          if (i2 < 0 || sc[e] > sc[i2]) i2 = e;
        }
        float w1 = sc[i1], w2 = sc[i2];
        float inv = 1.f / (w1 + w2 + 1e-8f);
        topi[t] = make_int2(i1, i2);
        topw[t] = make_float2(w1 * inv, w2 * inv);
      }
    } else {
      size_t j = ((size_t)(u - NWB - NRB) * 256 + tid) * 4;
      f32x4 zz = {0.f, 0.f, 0.f, 0.f};
      *(f32x4*)(out + j) = zz;
    }
  }
  gsync(bar + 0);

  // ============ P1: build lists (blocks 0..7, one per expert) ============
  if (bid < NE) {
    const int e = bid;
    const int wave = tid >> 6, lane = tid & 63;
    int* wc = rows_s;
    float* wf = (float*)(rows_s + 8);
    const int tbeg = wave * (NT / 4), tend = tbeg + NT / 4;
    int c = 0;
    float wa = 0.f;
    for (int t0 = tbeg; t0 < tend; t0 += 64) {
      int2 ti = topi[t0 + lane];
      float2 tw = topw[t0 + lane];
      bool hit = (ti.x == e) || (ti.y == e);
      float w = (ti.x == e) ? tw.x : ((ti.y == e) ? tw.y : 0.f);
      c += __popcll(__ballot(hit));
#pragma unroll
      for (int off = 32; off > 0; off >>= 1) w += __shfl_xor(w, off);
      wa += w;
    }
    if (lane == 0) { wc[wave] = c; wf[wave] = wa; }
    __syncthreads();
    int pos = 0;
    for (int w = 0; w < wave; w++) pos += wc[w];
    for (int t0 = tbeg; t0 < tend; t0 += 64) {
      int t = t0 + lane;
      int2 ti = topi[t];
      bool hit = (ti.x == e) || (ti.y == e);
      unsigned long long m = __ballot(hit);
      int pre = __popcll(m & ((1ull << lane) - 1ull));
      if (hit) lists[e * NT + pos + pre] = t;
      pos += __popcll(m);
    }
    if (tid == 0) {
      int ctot = wc[0] + wc[1] + wc[2] + wc[3];
      cnt[e] = ctot;
      wm[e] = (wf[0] + wf[1] + wf[2] + wf[3]) / (float)(ctot > 0 ? ctot : 1);
    }
  }
  gsync(bar + 16);

  const int lane = tid & 63, wave = tid >> 6;
  const int mw = (wave & 1) * 32, nw = (wave >> 1) * 64;
  const int l15 = lane & 15, quad = lane >> 4;
  const int srow = tid >> 3;   // 0..31
  const int cch = tid & 7;     // 16B chunk id
  const int p8 = cch * 8;
  const int sx = (l15 & 7) * 8;

  // ============ P2: gate+up GEMM, 64x128 tiles (R1-proven inner loop) ====
  // vb<512: shared (ct=s&15, rt=s>>4). vb>=512: routed r0=vb-512:
  // z=r0&7, ct=(r0>>3)&7, rt=r0>>6 (real tiles rt<~8 -> vb<1024).
  for (int vb = bid; vb < 2560; vb += GRID) {
    int z, ct, rt;
    if (vb < 512) { z = NE; ct = vb & 15; rt = vb >> 4; }
    else { int r0 = vb - 512; z = r0 & 7; ct = (r0 >> 3) & 7; rt = r0 >> 6; }
    int mrem, ldc;
    bf16* Cb;
    const bf16* Bb;
    if (z < NE) {
      int c = cnt[z];
      if (rt * 64 >= c) continue;
      mrem = c - rt * 64;
      Bb = wb + W_GU + ((size_t)z << 20) + (size_t)ct * 128 * H_DIM;
      Cb = act_e + ((size_t)z * NT + rt * 64) * I_DIM;
      ldc = I_DIM;
    } else {
      mrem = 64;
      Bb = wb + W_SGU + (size_t)ct * 128 * H_DIM;
      Cb = act_s + (size_t)rt * 64 * SI_DIM;
      ldc = SI_DIM;
    }
    if (tid < 64)
      rows_s[tid] = (z < NE)
          ? lists[z * NT + rt * 64 + (tid < mrem ? tid : mrem - 1)]
          : rt * 64 + tid;
    __syncthreads();
    const bf16 *ap[2], *bp[4];
    int alo[2], blo[4];
#pragma unroll
    for (int r = 0; r < 2; r++) {
      int R = srow + r * 32;
      int gs = (cch ^ (R & 7)) * 8;
      ap[r] = xb + (size_t)rows_s[R] * H_DIM + gs;
      alo[r] = R * 64 + p8;
    }
#pragma unroll
    for (int r = 0; r < 4; r++) {
      int R = srow + r * 32;
      int gs = (cch ^ (R & 7)) * 8;
      bp[r] = Bb + (size_t)R * H_DIM + gs;
      blo[r] = R * 64 + p8;
    }
    f32x4 acc[2][4] = {};
    for (int k0 = 0; k0 < H_DIM; k0 += 64) {
#pragma unroll
      for (int r = 0; r < 2; r++) glds16(ap[r] + k0, &As[alo[r]]);
#pragma unroll
      for (int r = 0; r < 4; r++) glds16(bp[r] + k0, &Bs[blo[r]]);
      __syncthreads();
#pragma unroll
      for (int kk = 0; kk < 2; kk++) {
        const int ko = (kk * 4 + quad) * 8;
        bf16x8 av[2], bv[4];
#pragma unroll
        for (int i = 0; i < 2; i++)
          av[i] = *(const bf16x8*)&As[(mw + i * 16 + l15) * 64 + (ko ^ sx)];
#pragma unroll
        for (int j = 0; j < 4; j++)
          bv[j] = *(const bf16x8*)&Bs[(nw + j * 16 + l15) * 64 + (ko ^ sx)];
#pragma unroll
        for (int i = 0; i < 2; i++)
#pragma unroll
          for (int j = 0; j < 4; j++)
            acc[i][j] = __builtin_amdgcn_mfma_f32_16x16x32_bf16(
                av[i], bv[j], acc[i][j], 0, 0, 0);
      }
      __syncthreads();
    }
    // j even = gate, j odd = up
#pragma unroll
    for (int i = 0; i < 2; i++) {
#pragma unroll
      for (int rg = 0; rg < 4; rg++) {
        int rl = mw + i * 16 + quad * 4 + rg;
        if (rl < mrem) {
#pragma unroll
          for (int jp = 0; jp < 2; jp++) {
            float g = acc[i][jp * 2][rg];
            float u = acc[i][jp * 2 + 1][rg];
            int c = ct * 64 + (nw >> 1) + jp * 16 + l15;
            Cb[(size_t)rl * ldc + c] = (bf16)((g / (1.f + __expf(-g))) * u);
          }
        }
      }
    }
    __syncthreads();
  }
  gsync(bar + 32);

  // ============ P3: down GEMM, 64x128 tiles; atomicAdd epilogue ============
  // vb<256: shared (ct=vb&7, rt=vb>>3). vb>=256: routed r0=vb-256.
  for (int vb = bid; vb < 2304; vb += GRID) {
    int z, ct, rt;
    if (vb < 256) { z = NE; ct = vb & 7; rt = vb >> 3; }
    else { int r0 = vb - 256; z = r0 & 7; ct = (r0 >> 3) & 7; rt = r0 >> 6; }
    int K, mrem;
    const bf16 *Ab, *Bb;
    if (z < NE) {
      int c = cnt[z];
      if (rt * 64 >= c) continue;
      mrem = c - rt * 64;
      Ab = act_e + ((size_t)z * NT + rt * 64) * I_DIM;
      K = I_DIM;
      Bb = wb + W_DN + ((size_t)z << 19) + (size_t)ct * 128 * I_DIM;
    } else {
      mrem = 64;
      Ab = act_s + (size_t)rt * 64 * SI_DIM;
      K = SI_DIM;
      Bb = wb + W_SDN + (size_t)ct * 128 * SI_DIM;
    }
    if (tid < 64)
      rows_s[tid] = (z < NE)
          ? lists[z * NT + rt * 64 + (tid < mrem ? tid : mrem - 1)]
          : rt * 64 + tid;
    __syncthreads();
    const bf16 *ap[2], *bp[4];
    int alo[2], blo[4];
#pragma unroll
    for (int r = 0; r < 2; r++) {
      int R = srow + r * 32;
      int gs = (cch ^ (R & 7)) * 8;
      ap[r] = Ab + (size_t)R * K + gs;
      alo[r] = R * 64 + p8;
    }
#pragma unroll
    for (int r = 0; r < 4; r++) {
      int R = srow + r * 32;
      int gs = (cch ^ (R & 7)) * 8;
      bp[r] = Bb + (size_t)R * K + gs;
      blo[r] = R * 64 + p8;
    }
    f32x4 acc[2][4] = {};
    for (int k0 = 0; k0 < K; k0 += 64) {
#pragma unroll
      for (int r = 0; r < 2; r++) glds16(ap[r] + k0, &As[alo[r]]);
#pragma unroll
      for (int r = 0; r < 4; r++) glds16(bp[r] + k0, &Bs[blo[r]]);
      __syncthreads();
#pragma unroll
      for (int kk = 0; kk < 2; kk++) {
        const int ko = (kk * 4 + quad) * 8;
        bf16x8 av[2], bv[4];
#pragma unroll
        for (int i = 0; i < 2; i++)
          av[i] = *(const bf16x8*)&As[(mw + i * 16 + l15) * 64 + (ko ^ sx)];
#pragma unroll
        for (int j = 0; j < 4; j++)
          bv[j] = *(const bf16x8*)&Bs[(nw + j * 16 + l15) * 64 + (ko ^ sx)];
#pragma unroll
        for (int i = 0; i < 2; i++)
#pragma unroll
          for (int j = 0; j < 4; j++)
            acc[i][j] = __builtin_amdgcn_mfma_f32_16x16x32_bf16(
                av[i], bv[j], acc[i][j], 0, 0, 0);
      }
      __syncthreads();
    }
    const float wsc = (z < NE) ? wm[z] : 1.f;
#pragma unroll
    for (int i = 0; i < 2; i++) {
#pragma unroll
      for (int rg = 0; rg < 4; rg++) {
        int rl = mw + i * 16 + quad * 4 + rg;
        if (rl < mrem) {
          int t = rows_s[rl];
          float* orow = out + (size_t)t * H_DIM + ct * 128 + nw;
#pragma unroll
          for (int j = 0; j < 4; j++)
            atomicAdd(&orow[j * 16 + l15], wsc * acc[i][j][rg]);
        }
      }
    }
    __syncthreads();
  }
}

extern "C" void kernel_launch(void* const* d_in, const int* in_sizes, int n_in,
                              void* d_out, int out_size, void* d_ws,
                              size_t ws_size, hipStream_t stream) {
  (void)in_sizes; (void)n_in; (void)out_size; (void)ws_size;
  const float* x  = (const float*)d_in[0];
  const float* gw = (const float*)d_in[1];
  const float* lb = (const float*)d_in[2];
  const float* eg = (const float*)d_in[3];
  const float* eu = (const float*)d_in[4];
  const float* ed = (const float*)d_in[5];
  const float* sg = (const float*)d_in[6];
  const float* su = (const float*)d_in[7];
  const float* sd = (const float*)d_in[8];
  float* out = (float*)d_out;
  char* ws = (char*)d_ws;

  int* cnt     = (int*)(ws + OFF_CNT);
  float* wm    = (float*)(ws + OFF_WM);
  int2* topi   = (int2*)(ws + OFF_TOPI);
  float2* topw = (float2*)(ws + OFF_TOPW);
  int* lists   = (int*)(ws + OFF_LISTS);
  bf16* wb     = (bf16*)(ws + OFF_WB);
  bf16* xb     = (bf16*)(ws + OFF_XB);
  bf16* act_e  = (bf16*)(ws + OFF_ACTE);
  bf16* act_s  = (bf16*)(ws + OFF_ACTS);
  unsigned* bar = (unsigned*)(ws + OFF_BAR);

  hipMemsetAsync(bar, 0, 256, stream);
  moe_kernel<<<GRID, 256, 0, stream>>>(x, gw, lb, eg, eu, ed, sg, su, sd, wb,
                                       xb, topi, topw, cnt, wm, lists, act_e,
                                       act_s, out, bar);
}

// Round 7
// 215.859 us; speedup vs baseline: 2.3932x; 2.0552x over previous
//
#include <hip/hip_runtime.h>

#define H_DIM 1024
#define I_DIM 512
#define NE 8
#define SI_DIM 1024
#define NT 2048

typedef __bf16 bf16;
typedef __bf16 bf16x4 __attribute__((ext_vector_type(4)));
typedef __bf16 bf16x8 __attribute__((ext_vector_type(8)));
typedef float f32x4 __attribute__((ext_vector_type(4)));

// ---- bf16 weight buffer layout (elements), R4-verified interleave ----
#define W_GU 0ull
#define W_DN 8388608ull
#define W_SGU 12582912ull
#define W_SDN 14680064ull
#define W_TOT 15728640ull

#define NWB 15360  // weight-convert blocks
#define NRB 512    // router blocks (router also writes xb)
#define NZB 2048   // out-zeroing blocks (replaces hipMemsetAsync)

// ---- workspace (bytes, 16B aligned) ----
#define OFF_CNT 0
#define OFF_WM 64
#define OFF_TOPI 1024
#define OFF_TOPW (OFF_TOPI + NT * 8)
#define OFF_LISTS (OFF_TOPW + NT * 8)
#define OFF_WB (OFF_LISTS + NE * NT * 4)                  // bf16[W_TOT]
#define OFF_XB (OFF_WB + (size_t)W_TOT * 2)               // bf16[NT][H]
#define OFF_ACTE (OFF_XB + (size_t)NT * H_DIM * 2)        // bf16[NE][NT][I]
#define OFF_ACTS (OFF_ACTE + (size_t)NE * NT * I_DIM * 2) // bf16[NT][SI]

__device__ __forceinline__ bf16x4 cvt4(f32x4 v) {
  bf16x4 r;
  r.x = (bf16)v.x; r.y = (bf16)v.y; r.z = (bf16)v.z; r.w = (bf16)v.w;
  return r;
}

__device__ __forceinline__ void glds16(const bf16* g, bf16* l) {
  __builtin_amdgcn_global_load_lds(
      (const __attribute__((address_space(1))) unsigned int*)g,
      (__attribute__((address_space(3))) unsigned int*)l, 16, 0, 0);
}

// ---- prep: weight convert + router(+x-convert) + out zero (R3-proven) ----
__global__ __launch_bounds__(256) void prep_kernel(
    const float* __restrict__ x, const float* __restrict__ gw,
    const float* __restrict__ lb, const float* __restrict__ eg,
    const float* __restrict__ eu, const float* __restrict__ ed,
    const float* __restrict__ sg, const float* __restrict__ su,
    const float* __restrict__ sd, bf16* __restrict__ wb,
    bf16* __restrict__ xb, int2* __restrict__ topi,
    float2* __restrict__ topw, float* __restrict__ out) {
  const int bx = blockIdx.x;
  const int tid = threadIdx.x;
  if (bx < NWB) {
    size_t i = ((size_t)bx * 256 + tid) * 4;
    const float* src;
    if (i < W_DN) {
      size_t z = i >> 20;
      int rem = (int)(i & ((1u << 20) - 1));
      int rp = rem >> 10, k = rem & 1023;
      int b = rp >> 4;
      int sr = ((b >> 1) << 4) | (rp & 15);
      src = ((b & 1) ? eu : eg) + (z << 19) + ((size_t)sr << 10) + k;
    } else if (i < W_SGU) {
      src = ed + (i - W_DN);
    } else if (i < W_SDN) {
      int rem = (int)(i - W_SGU);
      int rp = rem >> 10, k = rem & 1023;
      int b = rp >> 4;
      int sr = ((b >> 1) << 4) | (rp & 15);
      src = ((b & 1) ? su : sg) + ((size_t)sr << 10) + k;
    } else {
      src = sd + (i - W_SDN);
    }
    *(bf16x4*)(wb + i) = cvt4(*(const f32x4*)src);
  } else if (bx < NWB + NRB) {
    const int lane = tid & 63;
    const int t = (bx - NWB) * 4 + (tid >> 6);
    const float* xr = x + (size_t)t * H_DIM;
    bf16* xw = xb + (size_t)t * H_DIM;
    float s[NE];
#pragma unroll
    for (int e = 0; e < NE; e++) s[e] = 0.f;
#pragma unroll
    for (int k0 = 0; k0 < H_DIM; k0 += 256) {
      f32x4 xv = *(const f32x4*)(xr + k0 + lane * 4);
      *(bf16x4*)(xw + k0 + lane * 4) = cvt4(xv);
#pragma unroll
      for (int e = 0; e < NE; e++) {
        f32x4 gv = *(const f32x4*)(gw + e * H_DIM + k0 + lane * 4);
        s[e] += xv.x * gv.x + xv.y * gv.y + xv.z * gv.z + xv.w * gv.w;
      }
    }
#pragma unroll
    for (int e = 0; e < NE; e++) {
      float v = s[e];
#pragma unroll
      for (int off = 32; off > 0; off >>= 1) v += __shfl_xor(v, off);
      s[e] = v;
    }
    if (lane == 0) {
      float sc[NE];
#pragma unroll
      for (int e = 0; e < NE; e++) sc[e] = 1.f / (1.f + expf(-(s[e] + lb[e])));
      int i1 = 0;
#pragma unroll
      for (int e = 1; e < NE; e++)
        if (sc[e] > sc[i1]) i1 = e;  // ties -> lowest index (lax.top_k)
      int i2 = -1;
#pragma unroll
      for (int e = 0; e < NE; e++) {
        if (e == i1) continue;
        if (i2 < 0 || sc[e] > sc[i2]) i2 = e;
      }
      float w1 = sc[i1], w2 = sc[i2];
      float inv = 1.f / (w1 + w2 + 1e-8f);
      topi[t] = make_int2(i1, i2);
      topw[t] = make_float2(w1 * inv, w2 * inv);
    }
  } else {
    size_t j = ((size_t)(bx - NWB - NRB) * 256 + tid) * 4;
    f32x4 zz = {0.f, 0.f, 0.f, 0.f};
    *(f32x4*)(out + j) = zz;
  }
}

// ---- gate+up GEMM: 64x128 tiles, inline ballot-scan list build (no build
// kernel). Grid 1536: b<1024 routed (z=b&7 -> XCD z, ct=(b>>3)&7, rt0=b>>6,
// stride-16 rt loop); b>=1024 shared (s=b-1024: ct=s&15, rt=s>>4, 1 tile).
__global__ __launch_bounds__(256) void gemm_gu(
    const bf16* __restrict__ wb, const bf16* __restrict__ xb,
    const int2* __restrict__ topi, bf16* __restrict__ act_e,
    bf16* __restrict__ act_s) {
  const int b = blockIdx.x;
  const int tid = threadIdx.x;
  const int lane = tid & 63, wave = tid >> 6;
  __shared__ __align__(16) bf16 As[64 * 64];
  __shared__ __align__(16) bf16 Bs[128 * 64];
  __shared__ int list_s[NT];
  __shared__ int cnt_s;

  int z, ct, rt0, rstride;
  if (b < 1024) {
    z = b & 7; ct = (b >> 3) & 7; rt0 = b >> 6; rstride = 16;
  } else {
    int s = b - 1024; z = NE; ct = s & 15; rt0 = s >> 4; rstride = 32;
  }

  // build this expert's token list in LDS (wave 0), identity for shared
  if (z < NE) {
    if (wave == 0) {
      int pos = 0;
      for (int t0 = 0; t0 < NT; t0 += 64) {
        int2 ti = topi[t0 + lane];
        bool hit = (ti.x == z) || (ti.y == z);
        unsigned long long m = __ballot(hit);
        int pre = __popcll(m & ((1ull << lane) - 1ull));
        if (hit) list_s[pos + pre] = t0 + lane;
        pos += __popcll(m);
      }
      if (lane == 0) cnt_s = pos;
    }
  } else {
    for (int i = tid; i < NT; i += 256) list_s[i] = i;
    if (tid == 0) cnt_s = NT;
  }
  __syncthreads();
  const int c = cnt_s;

  const int mw = (wave & 1) * 32, nw = (wave >> 1) * 64;
  const int l15 = lane & 15, quad = lane >> 4;
  const int srow = tid >> 3;   // 0..31
  const int cch = tid & 7;     // 16B chunk id
  const int p8 = cch * 8;
  const int sx = (l15 & 7) * 8;

  const bf16* Bb = (z < NE)
      ? wb + W_GU + ((size_t)z << 20) + (size_t)ct * 128 * H_DIM
      : wb + W_SGU + (size_t)ct * 128 * H_DIM;
  bf16* Cbase = (z < NE) ? act_e + (size_t)z * NT * I_DIM : act_s;
  const int ldc = (z < NE) ? I_DIM : SI_DIM;

  const bf16* bp[4];
  int blo[4];
#pragma unroll
  for (int r = 0; r < 4; r++) {
    int R = srow + r * 32;
    int gs = (cch ^ (R & 7)) * 8;
    bp[r] = Bb + (size_t)R * H_DIM + gs;
    blo[r] = R * 64 + p8;
  }

  for (int rtv = rt0; rtv * 64 < c; rtv += rstride) {
    const int mr = c - rtv * 64;
    const int gmr = mr < 64 ? mr : 64;
    const bf16* ap[2];
    int alo[2];
#pragma unroll
    for (int r = 0; r < 2; r++) {
      int R = srow + r * 32;
      int gs = (cch ^ (R & 7)) * 8;
      int row = list_s[rtv * 64 + (R < gmr ? R : gmr - 1)];
      ap[r] = xb + (size_t)row * H_DIM + gs;
      alo[r] = R * 64 + p8;
    }
    f32x4 acc[2][4] = {};
    for (int k0 = 0; k0 < H_DIM; k0 += 64) {
#pragma unroll
      for (int r = 0; r < 2; r++) glds16(ap[r] + k0, &As[alo[r]]);
#pragma unroll
      for (int r = 0; r < 4; r++) glds16(bp[r] + k0, &Bs[blo[r]]);
      __syncthreads();
#pragma unroll
      for (int kk = 0; kk < 2; kk++) {
        const int ko = (kk * 4 + quad) * 8;
        bf16x8 av[2], bv[4];
#pragma unroll
        for (int i = 0; i < 2; i++)
          av[i] = *(const bf16x8*)&As[(mw + i * 16 + l15) * 64 + (ko ^ sx)];
#pragma unroll
        for (int j = 0; j < 4; j++)
          bv[j] = *(const bf16x8*)&Bs[(nw + j * 16 + l15) * 64 + (ko ^ sx)];
#pragma unroll
        for (int i = 0; i < 2; i++)
#pragma unroll
          for (int j = 0; j < 4; j++)
            acc[i][j] = __builtin_amdgcn_mfma_f32_16x16x32_bf16(
                av[i], bv[j], acc[i][j], 0, 0, 0);
      }
      __syncthreads();
    }
    // j even = gate, j odd = up
    bf16* Cb = Cbase + (size_t)rtv * 64 * ldc;
#pragma unroll
    for (int i = 0; i < 2; i++) {
#pragma unroll
      for (int rg = 0; rg < 4; rg++) {
        int rl = mw + i * 16 + quad * 4 + rg;
        if (rl < gmr) {
#pragma unroll
          for (int jp = 0; jp < 2; jp++) {
            float g = acc[i][jp * 2][rg];
            float u = acc[i][jp * 2 + 1][rg];
            int cc = ct * 64 + (nw >> 1) + jp * 16 + l15;
            Cb[(size_t)rl * ldc + cc] = (bf16)((g / (1.f + __expf(-g))) * u);
          }
        }
      }
    }
  }
}

// ---- down GEMM: 64x128 tiles, inline scan (also wm); atomicAdd(out).
// Grid 1280: b<1024 routed (z=b&7, ct=(b>>3)&7, rt0=b>>6, stride 16);
// b>=1024 shared (s<256: ct=s&7, rt=s>>3, 1 tile).
__global__ __launch_bounds__(256) void gemm_down(
    const bf16* __restrict__ wb, const bf16* __restrict__ act_e,
    const bf16* __restrict__ act_s, const int2* __restrict__ topi,
    const float2* __restrict__ topw, float* __restrict__ out) {
  const int b = blockIdx.x;
  const int tid = threadIdx.x;
  const int lane = tid & 63, wave = tid >> 6;
  __shared__ __align__(16) bf16 As[64 * 64];
  __shared__ __align__(16) bf16 Bs[128 * 64];
  __shared__ int list_s[NT];
  __shared__ int cnt_s;
  __shared__ float wm_s;

  int z, ct, rt0, rstride;
  if (b < 1024) {
    z = b & 7; ct = (b >> 3) & 7; rt0 = b >> 6; rstride = 16;
  } else {
    int s = b - 1024; z = NE; ct = s & 7; rt0 = s >> 3; rstride = 32;
  }

  if (z < NE) {
    if (wave == 0) {
      int pos = 0;
      float wacc = 0.f;
      for (int t0 = 0; t0 < NT; t0 += 64) {
        int2 ti = topi[t0 + lane];
        float2 tw = topw[t0 + lane];
        bool hit = (ti.x == z) || (ti.y == z);
        unsigned long long m = __ballot(hit);
        int pre = __popcll(m & ((1ull << lane) - 1ull));
        if (hit) {
          list_s[pos + pre] = t0 + lane;
          wacc += (ti.x == z) ? tw.x : tw.y;
        }
        pos += __popcll(m);
      }
#pragma unroll
      for (int off = 32; off > 0; off >>= 1) wacc += __shfl_xor(wacc, off);
      if (lane == 0) {
        cnt_s = pos;
        wm_s = wacc / (float)(pos > 0 ? pos : 1);
      }
    }
  } else {
    for (int i = tid; i < NT; i += 256) list_s[i] = i;
    if (tid == 0) { cnt_s = NT; wm_s = 1.f; }
  }
  __syncthreads();
  const int c = cnt_s;
  const float wsc = wm_s;

  const int mw = (wave & 1) * 32, nw = (wave >> 1) * 64;
  const int l15 = lane & 15, quad = lane >> 4;
  const int srow = tid >> 3;
  const int cch = tid & 7;
  const int p8 = cch * 8;
  const int sx = (l15 & 7) * 8;

  const int K = (z < NE) ? I_DIM : SI_DIM;
  const bf16* Bb = (z < NE)
      ? wb + W_DN + ((size_t)z << 19) + (size_t)ct * 128 * I_DIM
      : wb + W_SDN + (size_t)ct * 128 * SI_DIM;
  const bf16* Abase = (z < NE) ? act_e + (size_t)z * NT * I_DIM : act_s;

  const bf16* bp[4];
  int blo[4];
#pragma unroll
  for (int r = 0; r < 4; r++) {
    int R = srow + r * 32;
    int gs = (cch ^ (R & 7)) * 8;
    bp[r] = Bb + (size_t)R * K + gs;
    blo[r] = R * 64 + p8;
  }

  for (int rtv = rt0; rtv * 64 < c; rtv += rstride) {
    const int mr = c - rtv * 64;
    const int gmr = mr < 64 ? mr : 64;
    const bf16* Ab = Abase + (size_t)rtv * 64 * K;
    const bf16* ap[2];
    int alo[2];
#pragma unroll
    for (int r = 0; r < 2; r++) {
      int R = srow + r * 32;
      int gs = (cch ^ (R & 7)) * 8;
      ap[r] = Ab + (size_t)R * K + gs;
      alo[r] = R * 64 + p8;
    }
    f32x4 acc[2][4] = {};
    for (int k0 = 0; k0 < K; k0 += 64) {
#pragma unroll
      for (int r = 0; r < 2; r++) glds16(ap[r] + k0, &As[alo[r]]);
#pragma unroll
      for (int r = 0; r < 4; r++) glds16(bp[r] + k0, &Bs[blo[r]]);
      __syncthreads();
#pragma unroll
      for (int kk = 0; kk < 2; kk++) {
        const int ko = (kk * 4 + quad) * 8;
        bf16x8 av[2], bv[4];
#pragma unroll
        for (int i = 0; i < 2; i++)
          av[i] = *(const bf16x8*)&As[(mw + i * 16 + l15) * 64 + (ko ^ sx)];
#pragma unroll
        for (int j = 0; j < 4; j++)
          bv[j] = *(const bf16x8*)&Bs[(nw + j * 16 + l15) * 64 + (ko ^ sx)];
#pragma unroll
        for (int i = 0; i < 2; i++)
#pragma unroll
          for (int j = 0; j < 4; j++)
            acc[i][j] = __builtin_amdgcn_mfma_f32_16x16x32_bf16(
                av[i], bv[j], acc[i][j], 0, 0, 0);
      }
      __syncthreads();
    }
#pragma unroll
    for (int i = 0; i < 2; i++) {
#pragma unroll
      for (int rg = 0; rg < 4; rg++) {
        int rl = mw + i * 16 + quad * 4 + rg;
        if (rl < gmr) {
          int t = list_s[rtv * 64 + rl];
          float* orow = out + (size_t)t * H_DIM + ct * 128 + nw;
#pragma unroll
          for (int j = 0; j < 4; j++)
            atomicAdd(&orow[j * 16 + l15], wsc * acc[i][j][rg]);
        }
      }
    }
  }
}

extern "C" void kernel_launch(void* const* d_in, const int* in_sizes, int n_in,
                              void* d_out, int out_size, void* d_ws,
                              size_t ws_size, hipStream_t stream) {
  (void)in_sizes; (void)n_in; (void)out_size; (void)ws_size;
  const float* x  = (const float*)d_in[0];
  const float* gw = (const float*)d_in[1];
  const float* lb = (const float*)d_in[2];
  const float* eg = (const float*)d_in[3];
  const float* eu = (const float*)d_in[4];
  const float* ed = (const float*)d_in[5];
  const float* sg = (const float*)d_in[6];
  const float* su = (const float*)d_in[7];
  const float* sd = (const float*)d_in[8];
  float* out = (float*)d_out;
  char* ws = (char*)d_ws;

  int2* topi   = (int2*)(ws + OFF_TOPI);
  float2* topw = (float2*)(ws + OFF_TOPW);
  bf16* wb     = (bf16*)(ws + OFF_WB);
  bf16* xb     = (bf16*)(ws + OFF_XB);
  bf16* act_e  = (bf16*)(ws + OFF_ACTE);
  bf16* act_s  = (bf16*)(ws + OFF_ACTS);

  prep_kernel<<<NWB + NRB + NZB, 256, 0, stream>>>(x, gw, lb, eg, eu, ed, sg,
                                                   su, sd, wb, xb, topi, topw,
                                                   out);
  gemm_gu<<<1536, 256, 0, stream>>>(wb, xb, topi, act_e, act_s);
  gemm_down<<<1280, 256, 0, stream>>>(wb, act_e, act_s, topi, topw, out);
}